// Round 2
// baseline (2251.826 us; speedup 1.0000x reference)
//
#include <hip/hip_runtime.h>

// ---------------- static graph constants (Traffic4cast 495x436 grid) -------
#define HH 495
#define WW 436
#define NN 215820          // HH*WW
#define NPOOL 54064        // 248*218 pooled nodes
#define PC 218             // pooled cols
#define EN 215384          // north/south edge count  (HH-1)*WW
#define EE 215325          // east/west edge count    HH*(WW-1)
#define KN 53846           // kept pooled edges north/south  247*218
#define KE 53816           // kept pooled edges east/west    248*217

// output layout offsets (in floats)
static constexpr size_t OFF_POS = (size_t)NPOOL * 128;           // 6,920,192
static constexpr size_t OFF_EIN = OFF_POS + (size_t)NPOOL * 2;   // 7,028,320
static constexpr size_t OFF_EIE = OFF_EIN + (size_t)KN * 2;      // 7,136,012
static constexpr size_t OFF_EIS = OFF_EIE + (size_t)KE * 2;      // 7,243,644
static constexpr size_t OFF_EIW = OFF_EIS + (size_t)KN * 2;      // 7,351,336
static constexpr size_t OFF_EFN = OFF_EIW + (size_t)KE * 2;      // 7,458,968
static constexpr size_t OFF_EFE = OFF_EFN + (size_t)KN * 32;     // 9,182,040
static constexpr size_t OFF_EFS = OFF_EFE + (size_t)KE * 32;     // 10,904,152
static constexpr size_t OFF_EFW = OFF_EFS + (size_t)KN * 32;     // 12,627,224
static constexpr size_t OUT_TOTAL = OFF_EFW + (size_t)KE * 32;   // 14,349,336

// ---------------------------------------------------------------------------
// Pattern used by all 3 matmul kernels: thread = node/edge (per-lane inputs,
// global->VGPR float4 coalesced), accumulators in VGPRs, W indexed ONLY by
// blockIdx/loop counters -> wave-uniform -> compiler emits s_load via the
// scalar cache (no LDS, no broadcast waste, v_fma with SGPR operand).
// ---------------------------------------------------------------------------

// Kernel A: xq[q][n][j] = relu(x[n,:] @ W_emb[q][:,j]).  blockIdx.y picks a
// PAIR of quadrants (x is read only 2x instead of 4x; acc = 64 VGPRs).
__global__ __launch_bounds__(256) void k_xq(const float* __restrict__ x,
                                            const float* __restrict__ W_emb,
                                            float* __restrict__ xq) {
  const int n = blockIdx.x * 256 + threadIdx.x;
  if (n >= NN) return;
  const int q0 = blockIdx.y * 2;
  const float* __restrict__ W0 = W_emb + (size_t)q0 * 4096;   // [128][32]
  const float* __restrict__ W1 = W0 + 4096;
  float acc0[32], acc1[32];
#pragma unroll
  for (int j = 0; j < 32; ++j) { acc0[j] = 0.f; acc1[j] = 0.f; }
  const float* __restrict__ xr = x + (size_t)n * 128;
#pragma unroll 1
  for (int kc = 0; kc < 16; ++kc) {          // k-chunks of 8
    const float4 a = *(const float4*)(xr + kc * 8);
    const float4 b = *(const float4*)(xr + kc * 8 + 4);
    const float in[8] = {a.x, a.y, a.z, a.w, b.x, b.y, b.z, b.w};
#pragma unroll
    for (int j = 0; j < 32; ++j) {
      float s0 = acc0[j], s1 = acc1[j];
#pragma unroll
      for (int k = 0; k < 8; ++k) {
        s0 = fmaf(in[k], W0[(kc * 8 + k) * 32 + j], s0);   // uniform -> s_load
        s1 = fmaf(in[k], W1[(kc * 8 + k) * 32 + j], s1);
      }
      acc0[j] = s0; acc1[j] = s1;
    }
  }
  float* o0 = xq + ((size_t)q0 * NN + n) * 32;
  float* o1 = o0 + (size_t)NN * 32;
#pragma unroll
  for (int jv = 0; jv < 8; ++jv) {
    float4 v0, v1;
    v0.x = fmaxf(acc0[4 * jv + 0], 0.f); v0.y = fmaxf(acc0[4 * jv + 1], 0.f);
    v0.z = fmaxf(acc0[4 * jv + 2], 0.f); v0.w = fmaxf(acc0[4 * jv + 3], 0.f);
    v1.x = fmaxf(acc1[4 * jv + 0], 0.f); v1.y = fmaxf(acc1[4 * jv + 1], 0.f);
    v1.z = fmaxf(acc1[4 * jv + 2], 0.f); v1.w = fmaxf(acc1[4 * jv + 3], 0.f);
    *(float4*)(o0 + 4 * jv) = v0;
    *(float4*)(o1 + 4 * jv) = v1;
  }
}

// ---------------------------------------------------------------------------
// 32-k segment accumulate for k_edge: acc[j] += in[0..31] @ Wq[S*32.., j]
template <int S>
__device__ __forceinline__ void seg_accum(const float* __restrict__ bp,
                                          const float* __restrict__ Wq,
                                          float acc[32]) {
#pragma unroll 2
  for (int kc = 0; kc < 4; ++kc) {
    const float4 a = *(const float4*)(bp + kc * 8);
    const float4 b = *(const float4*)(bp + kc * 8 + 4);
    const float in[8] = {a.x, a.y, a.z, a.w, b.x, b.y, b.z, b.w};
#pragma unroll
    for (int j = 0; j < 32; ++j) {
      float s = acc[j];
#pragma unroll
      for (int k = 0; k < 8; ++k)
        s = fmaf(in[k], Wq[(S * 32 + kc * 8 + k) * 32 + j], s);   // uniform
      acc[j] = s;
    }
  }
}

// Kernel B: per edge e of direction q (thread = edge):
//   feat = relu([ef[e], xq[src], xq[dst]] @ W_edge[q])          (96x32)
//   agg[dst][q*32+:] = feat*0.25   (each node has <=1 in-edge per direction)
//   kept groups: atomicMax into pooled efeat (values >= 0, out zeroed).
__global__ __launch_bounds__(256) void k_edge(
    const int* __restrict__ ei_n, const int* __restrict__ ei_e,
    const int* __restrict__ ei_s, const int* __restrict__ ei_w,
    const float* __restrict__ ef_n, const float* __restrict__ ef_e,
    const float* __restrict__ ef_s, const float* __restrict__ ef_w,
    const float* __restrict__ xq, const float* __restrict__ W_edge,
    float* __restrict__ agg, float* __restrict__ out) {
  const int q = blockIdx.y;
  const int* ei; const float* ef; int E; float* efb;
  if (q == 0)      { ei = ei_n; ef = ef_n; E = EN; efb = out + OFF_EFN; }
  else if (q == 1) { ei = ei_e; ef = ef_e; E = EE; efb = out + OFF_EFE; }
  else if (q == 2) { ei = ei_s; ef = ef_s; E = EN; efb = out + OFF_EFS; }
  else             { ei = ei_w; ef = ef_w; E = EE; efb = out + OFF_EFW; }
  const int e = blockIdx.x * 256 + threadIdx.x;
  if (e >= E) return;
  const int2 sd = *(const int2*)(ei + 2 * e);
  const int src = sd.x, dst = sd.y;
  const float* __restrict__ Wq  = W_edge + q * 3072;          // [96][32]
  const float* __restrict__ xqq = xq + (size_t)q * NN * 32;
  float acc[32];
#pragma unroll
  for (int j = 0; j < 32; ++j) acc[j] = 0.f;
  seg_accum<0>(ef + (size_t)e * 32,    Wq, acc);
  seg_accum<1>(xqq + (size_t)src * 32, Wq, acc);
  seg_accum<2>(xqq + (size_t)dst * 32, Wq, acc);
#pragma unroll
  for (int j = 0; j < 32; ++j) acc[j] = fmaxf(acc[j], 0.f);
  float* ar = agg + (size_t)dst * 128 + q * 32;
#pragma unroll
  for (int jv = 0; jv < 8; ++jv) {
    float4 v;
    v.x = acc[4 * jv + 0] * 0.25f; v.y = acc[4 * jv + 1] * 0.25f;
    v.z = acc[4 * jv + 2] * 0.25f; v.w = acc[4 * jv + 3] * 0.25f;
    *(float4*)(ar + 4 * jv) = v;
  }
  const int r = src / WW;
  const int c = src - r * WW;
  bool kept; int idx;
  if (q == 0)      { kept = (r & 1) == 0; idx = ((r >> 1) - 1) * 218 + (c >> 1); }
  else if (q == 1) { kept = (c & 1) == 1; idx = (r >> 1) * 217 + (c >> 1); }
  else if (q == 2) { kept = (r & 1) == 1; idx = (r >> 1) * 218 + (c >> 1); }
  else             { kept = (c & 1) == 0; idx = (r >> 1) * 217 + (c >> 1) - 1; }
  if (kept) {
    int* ob = (int*)(efb + (size_t)idx * 32);
#pragma unroll
    for (int j = 0; j < 32; ++j) atomicMax(ob + j, __float_as_int(acc[j]));
  }
}

// ---------------------------------------------------------------------------
// Kernel C: x2[n] = relu([x[n] | agg[n]] @ W_node) (256x128); atomicMax into
// x_pooled. thread = node, blockIdx.y = output half (64 cols, acc = 64 VGPRs).
__global__ __launch_bounds__(256) void k_node(const float* __restrict__ x,
                                              const float* __restrict__ agg,
                                              const float* __restrict__ W_node,
                                              float* __restrict__ out) {
  const int n = blockIdx.x * 256 + threadIdx.x;
  if (n >= NN) return;
  const int jh = blockIdx.y;                       // 0 or 1
  const float* __restrict__ Wb = W_node + jh * 64; // [256][128] col offset
  float acc[64];
#pragma unroll
  for (int j = 0; j < 64; ++j) acc[j] = 0.f;
  const float* __restrict__ xr = x + (size_t)n * 128;
#pragma unroll 1
  for (int kc = 0; kc < 16; ++kc) {
    const float4 a = *(const float4*)(xr + kc * 8);
    const float4 b = *(const float4*)(xr + kc * 8 + 4);
    const float in[8] = {a.x, a.y, a.z, a.w, b.x, b.y, b.z, b.w};
#pragma unroll
    for (int j = 0; j < 64; ++j) {
      float s = acc[j];
#pragma unroll
      for (int k = 0; k < 8; ++k)
        s = fmaf(in[k], Wb[(kc * 8 + k) * 128 + j], s);          // uniform
      acc[j] = s;
    }
  }
  const float* __restrict__ ar = agg + (size_t)n * 128;
#pragma unroll 1
  for (int kc = 0; kc < 16; ++kc) {
    const float4 a = *(const float4*)(ar + kc * 8);
    const float4 b = *(const float4*)(ar + kc * 8 + 4);
    const float in[8] = {a.x, a.y, a.z, a.w, b.x, b.y, b.z, b.w};
#pragma unroll
    for (int j = 0; j < 64; ++j) {
      float s = acc[j];
#pragma unroll
      for (int k = 0; k < 8; ++k)
        s = fmaf(in[k], Wb[(128 + kc * 8 + k) * 128 + j], s);    // uniform
      acc[j] = s;
    }
  }
  const int r = n / WW;
  const int c = n - r * WW;
  const int p = (r >> 1) * PC + (c >> 1);
  int* ob = (int*)(out + (size_t)p * 128 + jh * 64);
#pragma unroll
  for (int j = 0; j < 64; ++j)
    atomicMax(ob + j, __float_as_int(fmaxf(acc[j], 0.f)));
}

// ---------------------------------------------------------------------------
// Kernel D: closed-form new_pos + pooled edge indices (written as float).
__global__ __launch_bounds__(256) void k_misc(float* __restrict__ out) {
  int u = blockIdx.x * 256 + threadIdx.x;
  if (u < NPOOL * 2) {
    const int p  = u >> 1;
    const int pr = p / PC;
    const int pc = p - pr * PC;
    out[OFF_POS + u] = (float)((u & 1) ? pc : pr);
    return;
  }
  u -= NPOOL * 2;
  if (u < KN * 2) {   // north
    const int e  = u >> 1;
    const int kr = e / PC + 1;
    const int pc = e - (kr - 1) * PC;
    const int s  = kr * PC + pc;
    out[OFF_EIN + u] = (float)((u & 1) ? (s - PC) : s);
    return;
  }
  u -= KN * 2;
  if (u < KE * 2) {   // east
    const int e  = u >> 1;
    const int pr = e / 217;
    const int jj = e - pr * 217;
    const int s  = pr * PC + jj;
    out[OFF_EIE + u] = (float)((u & 1) ? (s + 1) : s);
    return;
  }
  u -= KE * 2;
  if (u < KN * 2) {   // south
    const int e  = u >> 1;
    const int k  = e / PC;
    const int pc = e - k * PC;
    const int s  = k * PC + pc;
    out[OFF_EIS + u] = (float)((u & 1) ? (s + PC) : s);
    return;
  }
  u -= KN * 2;
  if (u < KE * 2) {   // west
    const int e  = u >> 1;
    const int pr = e / 217;
    const int jj = e - pr * 217;
    const int s  = pr * PC + jj + 1;
    out[OFF_EIW + u] = (float)((u & 1) ? (s - 1) : s);
  }
}

// ---------------------------------------------------------------------------
extern "C" void kernel_launch(void* const* d_in, const int* in_sizes, int n_in,
                              void* d_out, int out_size, void* d_ws, size_t ws_size,
                              hipStream_t stream) {
  const float* x      = (const float*)d_in[0];
  const int*   ei_n   = (const int*)d_in[2];
  const int*   ei_e   = (const int*)d_in[3];
  const int*   ei_s   = (const int*)d_in[4];
  const int*   ei_w   = (const int*)d_in[5];
  const float* ef_n   = (const float*)d_in[6];
  const float* ef_e   = (const float*)d_in[7];
  const float* ef_s   = (const float*)d_in[8];
  const float* ef_w   = (const float*)d_in[9];
  const float* W_emb  = (const float*)d_in[10];
  const float* W_edge = (const float*)d_in[11];
  const float* W_node = (const float*)d_in[12];
  float* out = (float*)d_out;

  // workspace: xq [4][N][32] then agg [N][128]
  float* xq  = (float*)d_ws;
  float* agg = xq + (size_t)NN * 128;

  // zero-init only atomicMax target regions + agg (nodes missing an in-edge)
  hipMemsetAsync(out, 0, OFF_POS * sizeof(float), stream);
  hipMemsetAsync(out + OFF_EFN, 0, (OUT_TOTAL - OFF_EFN) * sizeof(float), stream);
  hipMemsetAsync(agg, 0, (size_t)NN * 128 * sizeof(float), stream);

  k_xq  <<<dim3((NN + 255) / 256, 2), 256, 0, stream>>>(x, W_emb, xq);
  k_edge<<<dim3((EN + 255) / 256, 4), 256, 0, stream>>>(
      ei_n, ei_e, ei_s, ei_w, ef_n, ef_e, ef_s, ef_w, xq, W_edge, agg, out);
  k_node<<<dim3((NN + 255) / 256, 2), 256, 0, stream>>>(x, agg, W_node, out);

  const int misc_total = NPOOL * 2 + 2 * (KN * 2 + KE * 2);
  k_misc<<<dim3((misc_total + 255) / 256), 256, 0, stream>>>(out);
}

// Round 3
// 591.916 us; speedup vs baseline: 3.8043x; 3.8043x over previous
//
#include <hip/hip_runtime.h>

// ---------------- static graph constants (Traffic4cast 495x436 grid) -------
#define NN 215820          // 495*436 nodes
#define NPOOL 54064        // 248*218 pooled nodes
#define KN 53846           // kept pooled edges north/south  247*218
#define KE 53816           // kept pooled edges east/west    248*217

// output layout offsets (in floats)
static constexpr size_t OFF_POS = (size_t)NPOOL * 128;
static constexpr size_t OFF_EIN = OFF_POS + (size_t)NPOOL * 2;
static constexpr size_t OFF_EIE = OFF_EIN + (size_t)KN * 2;
static constexpr size_t OFF_EIS = OFF_EIE + (size_t)KE * 2;
static constexpr size_t OFF_EIW = OFF_EIS + (size_t)KN * 2;
static constexpr size_t OFF_EFN = OFF_EIW + (size_t)KE * 2;
static constexpr size_t OFF_EFE = OFF_EFN + (size_t)KN * 32;
static constexpr size_t OFF_EFS = OFF_EFE + (size_t)KE * 32;
static constexpr size_t OFF_EFW = OFF_EFS + (size_t)KN * 32;

// ---------------------------------------------------------------------------
// Shared inner: one 32-k chunk of the 128x128 tile GEMM.
// xs: [128 rows][36], ws: [32 k][132 cols]. Thread rows {4ty+i, 64+4ty+i},
// cols {4tx..4tx+3, 64+4tx..64+4tx+3}  (split keeps LDS aliasing at 2-way).
__device__ __forceinline__ void gemm_chunk(const float* __restrict__ xs,
                                           const float* __restrict__ ws,
                                           const float* const xr[8],
                                           int tx4, float acc[8][8]) {
#pragma unroll 1
  for (int kb = 0; kb < 32; kb += 4) {
    float4 xv[8];
#pragma unroll
    for (int i = 0; i < 8; ++i) xv[i] = *(const float4*)(xr[i] + kb);
    float4 wl[4], wh[4];
#pragma unroll
    for (int kk = 0; kk < 4; ++kk) {
      wl[kk] = *(const float4*)(ws + (kb + kk) * 132 + tx4);
      wh[kk] = *(const float4*)(ws + (kb + kk) * 132 + tx4 + 64);
    }
#pragma unroll
    for (int i = 0; i < 8; ++i) {
      const float* xe = (const float*)&xv[i];
#pragma unroll
      for (int kk = 0; kk < 4; ++kk) {
        acc[i][0] = fmaf(xe[kk], wl[kk].x, acc[i][0]);
        acc[i][1] = fmaf(xe[kk], wl[kk].y, acc[i][1]);
        acc[i][2] = fmaf(xe[kk], wl[kk].z, acc[i][2]);
        acc[i][3] = fmaf(xe[kk], wl[kk].w, acc[i][3]);
        acc[i][4] = fmaf(xe[kk], wh[kk].x, acc[i][4]);
        acc[i][5] = fmaf(xe[kk], wh[kk].y, acc[i][5]);
        acc[i][6] = fmaf(xe[kk], wh[kk].z, acc[i][6]);
        acc[i][7] = fmaf(xe[kk], wh[kk].w, acc[i][7]);
      }
    }
  }
}

// ---------------------------------------------------------------------------
// Kernel A: xq[q][n][u] = relu(x @ W_emb[q]) for all 4 q at once.
// Tile: 128 nodes x 128 cols (cols = 4 quadrants x 32), K=128 in 4 chunks.
__global__ __launch_bounds__(256) void k_xq(const float* __restrict__ x,
                                            const float* __restrict__ W_emb,
                                            float* __restrict__ xq) {
  __shared__ float xs[128 * 36];
  __shared__ float ws[32 * 132];
  const int t  = threadIdx.x;
  const int tx = t & 15, ty = t >> 4;
  const int n0 = blockIdx.x * 128;
  const int srow = t >> 1, soff = (t & 1) * 16;
  int snode = n0 + srow; if (snode >= NN) snode = NN - 1;
  const float* sxa = x + (size_t)snode * 128 + soff;
  float* sxd = xs + srow * 36 + soff;

  int rowidx[8];
#pragma unroll
  for (int i = 0; i < 4; ++i) { rowidx[i] = 4 * ty + i; rowidx[4 + i] = 64 + 4 * ty + i; }
  const float* xr[8];
#pragma unroll
  for (int i = 0; i < 8; ++i) xr[i] = xs + rowidx[i] * 36;
  const int tx4 = tx * 4;

  float acc[8][8];
#pragma unroll
  for (int i = 0; i < 8; ++i)
#pragma unroll
    for (int j = 0; j < 8; ++j) acc[i][j] = 0.f;

  for (int kc = 0; kc < 4; ++kc) {
    __syncthreads();
#pragma unroll
    for (int i = 0; i < 4; ++i)
      *(float4*)(sxd + 4 * i) = *(const float4*)(sxa + kc * 32 + 4 * i);
#pragma unroll
    for (int i = 0; i < 4; ++i) {
      const int f = t * 16 + 4 * i, kk = f >> 7, c = f & 127;
      *(float4*)(ws + kk * 132 + c) =
          *(const float4*)(W_emb + (size_t)(c >> 5) * 4096 +
                           (size_t)(kc * 32 + kk) * 32 + (c & 31));
    }
    __syncthreads();
    gemm_chunk(xs, ws, xr, tx4, acc);
  }
  const int qlo = tx >> 3, ulo = tx4 & 31;
#pragma unroll
  for (int i = 0; i < 8; ++i) {
    const int n = n0 + rowidx[i];
    if (n < NN) {
      float4 v, u;
      v.x = fmaxf(acc[i][0], 0.f); v.y = fmaxf(acc[i][1], 0.f);
      v.z = fmaxf(acc[i][2], 0.f); v.w = fmaxf(acc[i][3], 0.f);
      u.x = fmaxf(acc[i][4], 0.f); u.y = fmaxf(acc[i][5], 0.f);
      u.z = fmaxf(acc[i][6], 0.f); u.w = fmaxf(acc[i][7], 0.f);
      *(float4*)(xq + ((size_t)qlo * NN + n) * 32 + ulo) = v;
      *(float4*)(xq + ((size_t)(qlo + 2) * NN + n) * 32 + ulo) = u;
    }
  }
}

// ---------------------------------------------------------------------------
// Kernel C: x2[n] = relu([x[n]|agg[n]] @ W_node) (256x128) and in-register
// 2x2 pooled max -> PLAIN stores (no atomics). Block = pooled row pr x 32
// pooled cols; A-tile = 128 nodes = two contiguous 64-node runs.
__global__ __launch_bounds__(256) void k_node(const float* __restrict__ x,
                                              const float* __restrict__ agg,
                                              const float* __restrict__ W_node,
                                              float* __restrict__ out) {
  __shared__ float xs[128 * 36];
  __shared__ float ws[32 * 132];
  const int t  = threadIdx.x;
  const int tx = t & 15, ty = t >> 4;
  const int pr  = blockIdx.y;          // 0..247
  const int pc0 = blockIdx.x * 32;     // 0..192
  const bool hasB = (pr < 247);        // node row 2pr+1 exists?

  const int srow = t >> 1, soff = (t & 1) * 16;
  int ra = (srow < 64) ? 2 * pr : 2 * pr + 1; if (ra > 494) ra = 494;
  int ca = 2 * pc0 + (srow & 63);      if (ca > 435) ca = 435;
  const size_t snode = (size_t)ra * 436 + ca;
  float* sxd = xs + srow * 36 + soff;

  const float* xr[8];
#pragma unroll
  for (int i = 0; i < 4; ++i) {
    xr[i]     = xs + (4 * ty + i) * 36;
    xr[4 + i] = xs + (64 + 4 * ty + i) * 36;
  }
  const int tx4 = tx * 4;
  float acc[8][8];
#pragma unroll
  for (int i = 0; i < 8; ++i)
#pragma unroll
    for (int j = 0; j < 8; ++j) acc[i][j] = 0.f;

  for (int kc = 0; kc < 8; ++kc) {
    __syncthreads();
    const float* src = (kc < 4) ? (x + snode * 128 + kc * 32 + soff)
                                : (agg + snode * 128 + (kc - 4) * 32 + soff);
#pragma unroll
    for (int i = 0; i < 4; ++i)
      *(float4*)(sxd + 4 * i) = *(const float4*)(src + 4 * i);
#pragma unroll
    for (int i = 0; i < 4; ++i) {
      const int f = t * 16 + 4 * i, kk = f >> 7, c = f & 127;
      *(float4*)(ws + kk * 132 + c) =
          *(const float4*)(W_node + (size_t)(kc * 32 + kk) * 128 + c);
    }
    __syncthreads();
    gemm_chunk(xs, ws, xr, tx4, acc);
  }
  // group j=0,1: pooled col pc0+2ty+j; members = acc rows {2j,2j+1,4+2j,5+2j}
#pragma unroll
  for (int j = 0; j < 2; ++j) {
    const int pc = pc0 + 2 * ty + j;
    if (pc < 218) {
      const int iA = 2 * j;
      float mlo[4], mhi[4];
#pragma unroll
      for (int cc = 0; cc < 4; ++cc) {
        float m = fmaxf(fmaxf(acc[iA][cc], acc[iA + 1][cc]), 0.f);
        float h = fmaxf(fmaxf(acc[iA][4 + cc], acc[iA + 1][4 + cc]), 0.f);
        if (hasB) {
          m = fmaxf(m, fmaxf(acc[4 + iA][cc], acc[5 + iA][cc]));
          h = fmaxf(h, fmaxf(acc[4 + iA][4 + cc], acc[5 + iA][4 + cc]));
        }
        mlo[cc] = m; mhi[cc] = h;
      }
      float* ob = out + ((size_t)pr * 218 + pc) * 128;
      *(float4*)(ob + tx4)      = make_float4(mlo[0], mlo[1], mlo[2], mlo[3]);
      *(float4*)(ob + 64 + tx4) = make_float4(mhi[0], mhi[1], mhi[2], mhi[3]);
    }
  }
}

// ---------------------------------------------------------------------------
// Kernel B: edge MLP, one 32-lane slot per PAIR of edges in the same pooled
// dup-group (closed-form indices). efeat = in-thread max -> plain store.
// wcol[96] persistent in VGPRs, amortized over ~26 pairs via grid-stride.
__global__ __launch_bounds__(256) void k_edge(
    const float* __restrict__ ef_n, const float* __restrict__ ef_e,
    const float* __restrict__ ef_s, const float* __restrict__ ef_w,
    const float* __restrict__ xq, const float* __restrict__ W_edge,
    float* __restrict__ agg, float* __restrict__ out) {
  const int q = blockIdx.y;
  const float* ef; float* efb; int P;
  if (q == 0)      { ef = ef_n; P = 107692; efb = out + OFF_EFN; }
  else if (q == 1) { ef = ef_e; P = 107880; efb = out + OFF_EFE; }
  else if (q == 2) { ef = ef_s; P = 107692; efb = out + OFF_EFS; }
  else             { ef = ef_w; P = 107880; efb = out + OFF_EFW; }
  const int j = threadIdx.x & 31, slot = threadIdx.x >> 5;
  const float* Wq = W_edge + q * 3072;
  float wcol[96];
#pragma unroll
  for (int k = 0; k < 96; ++k) wcol[k] = Wq[k * 32 + j];
  const float* xqq = xq + (size_t)q * NN * 32;
  __shared__ float ein[8][192];
  float* row = ein[slot];

  for (int p = blockIdx.x * 8 + slot; p < P; p += gridDim.x * 8) {
    int e1, src1, dst1, e2, src2, dst2, kidx; bool kept, has2;
    if (q == 0) {                       // north: pair cols 2pc,2pc+1, row r
      const int rp = p / 218, pc = p - rp * 218;
      const int r = rp + 1, c = 2 * pc;
      e1 = (r - 1) * 436 + c; e2 = e1 + 1;
      src1 = r * 436 + c; dst1 = src1 - 436;
      src2 = src1 + 1; dst2 = dst1 + 1; has2 = true;
      kept = (r & 1) == 0; kidx = ((r >> 1) - 1) * 218 + pc;
    } else if (q == 2) {                // south
      const int r = p / 218, pc = p - r * 218;
      const int c = 2 * pc;
      e1 = r * 436 + c; e2 = e1 + 1;
      src1 = e1; dst1 = src1 + 436;
      src2 = src1 + 1; dst2 = dst1 + 1; has2 = true;
      kept = (r & 1) == 1; kidx = (r >> 1) * 218 + pc;
    } else if (q == 1) {                // east: pair rows 2pr,2pr+1, col c
      const int pr = p / 435, c = p - pr * 435;
      e1 = 2 * pr * 435 + c; e2 = e1 + 435;
      src1 = 2 * pr * 436 + c; dst1 = src1 + 1;
      src2 = src1 + 436; dst2 = dst1 + 436;
      has2 = pr < 247;
      kept = (c & 1) == 1; kidx = pr * 217 + (c >> 1);
    } else {                            // west
      const int pr = p / 435, cm = p - pr * 435;
      const int c = cm + 1;
      e1 = 2 * pr * 435 + cm; e2 = e1 + 435;
      src1 = 2 * pr * 436 + c; dst1 = src1 - 1;
      src2 = src1 + 436; dst2 = dst1 + 436;
      has2 = pr < 247;
      kept = (c & 1) == 0; kidx = pr * 217 + (c >> 1) - 1;
    }
    const int e2c = has2 ? e2 : e1;
    const int s2c = has2 ? src2 : src1;
    const int d2c = has2 ? dst2 : dst1;
    row[j]       = ef[(size_t)e1 * 32 + j];
    row[32 + j]  = xqq[(size_t)src1 * 32 + j];
    row[64 + j]  = xqq[(size_t)dst1 * 32 + j];
    row[96 + j]  = ef[(size_t)e2c * 32 + j];
    row[128 + j] = xqq[(size_t)s2c * 32 + j];
    row[160 + j] = xqq[(size_t)d2c * 32 + j];
    // wave-private LDS row: compiler inserts lgkmcnt before dependent reads
    float a1 = 0.f, a2 = 0.f;
#pragma unroll
    for (int kq = 0; kq < 24; ++kq) {
      const float4 b1 = *(const float4*)&row[4 * kq];
      const float4 b2 = *(const float4*)&row[96 + 4 * kq];
      a1 = fmaf(b1.x, wcol[4 * kq + 0], a1); a1 = fmaf(b1.y, wcol[4 * kq + 1], a1);
      a1 = fmaf(b1.z, wcol[4 * kq + 2], a1); a1 = fmaf(b1.w, wcol[4 * kq + 3], a1);
      a2 = fmaf(b2.x, wcol[4 * kq + 0], a2); a2 = fmaf(b2.y, wcol[4 * kq + 1], a2);
      a2 = fmaf(b2.z, wcol[4 * kq + 2], a2); a2 = fmaf(b2.w, wcol[4 * kq + 3], a2);
    }
    const float f1 = fmaxf(a1, 0.f), f2 = fmaxf(a2, 0.f);
    agg[(size_t)dst1 * 128 + q * 32 + j] = f1 * 0.25f;
    if (has2) agg[(size_t)dst2 * 128 + q * 32 + j] = f2 * 0.25f;
    if (kept) efb[(size_t)kidx * 32 + j] = has2 ? fmaxf(f1, f2) : f1;
  }
}

// ---------------------------------------------------------------------------
// Kernel D: zero agg boundary strips (nodes with no in-edge per direction)
// + closed-form new_pos + pooled edge indices.
__global__ __launch_bounds__(256) void k_misc(float* __restrict__ out,
                                              float* __restrict__ agg) {
  int u = blockIdx.x * 256 + threadIdx.x;
  if (u < 436 * 32) {  // north: dst row 494 missing
    agg[((size_t)494 * 436 + (u >> 5)) * 128 + (u & 31)] = 0.f; return;
  }
  u -= 436 * 32;
  if (u < 495 * 32) {  // east: dst col 0 missing
    agg[(size_t)(u >> 5) * 436 * 128 + 32 + (u & 31)] = 0.f; return;
  }
  u -= 495 * 32;
  if (u < 436 * 32) {  // south: dst row 0 missing
    agg[(size_t)(u >> 5) * 128 + 64 + (u & 31)] = 0.f; return;
  }
  u -= 436 * 32;
  if (u < 495 * 32) {  // west: dst col 435 missing
    agg[((size_t)(u >> 5) * 436 + 435) * 128 + 96 + (u & 31)] = 0.f; return;
  }
  u -= 495 * 32;
  if (u < NPOOL * 2) {
    const int p  = u >> 1;
    const int pr = p / 218, pc = p - pr * 218;
    out[OFF_POS + u] = (float)((u & 1) ? pc : pr); return;
  }
  u -= NPOOL * 2;
  if (u < KN * 2) {   // north
    const int e  = u >> 1;
    const int kr = e / 218 + 1, pc = e - (kr - 1) * 218;
    const int s  = kr * 218 + pc;
    out[OFF_EIN + u] = (float)((u & 1) ? (s - 218) : s); return;
  }
  u -= KN * 2;
  if (u < KE * 2) {   // east
    const int e  = u >> 1;
    const int pr = e / 217, jj = e - pr * 217;
    const int s  = pr * 218 + jj;
    out[OFF_EIE + u] = (float)((u & 1) ? (s + 1) : s); return;
  }
  u -= KE * 2;
  if (u < KN * 2) {   // south
    const int e  = u >> 1;
    const int k  = e / 218, pc = e - k * 218;
    const int s  = k * 218 + pc;
    out[OFF_EIS + u] = (float)((u & 1) ? (s + 218) : s); return;
  }
  u -= KN * 2;
  if (u < KE * 2) {   // west
    const int e  = u >> 1;
    const int pr = e / 217, jj = e - pr * 217;
    const int s  = pr * 218 + jj + 1;
    out[OFF_EIW + u] = (float)((u & 1) ? (s - 1) : s);
  }
}

// ---------------------------------------------------------------------------
extern "C" void kernel_launch(void* const* d_in, const int* in_sizes, int n_in,
                              void* d_out, int out_size, void* d_ws, size_t ws_size,
                              hipStream_t stream) {
  const float* x      = (const float*)d_in[0];
  const float* ef_n   = (const float*)d_in[6];
  const float* ef_e   = (const float*)d_in[7];
  const float* ef_s   = (const float*)d_in[8];
  const float* ef_w   = (const float*)d_in[9];
  const float* W_emb  = (const float*)d_in[10];
  const float* W_edge = (const float*)d_in[11];
  const float* W_node = (const float*)d_in[12];
  float* out = (float*)d_out;

  float* xq  = (float*)d_ws;                 // [4][NN][32]
  float* agg = xq + (size_t)NN * 128;        // [NN][128]

  const int misc_total = (436 + 495 + 436 + 495) * 32 + NPOOL * 2 +
                         2 * (KN * 2 + KE * 2);
  k_misc<<<dim3((misc_total + 255) / 256), 256, 0, stream>>>(out, agg);
  k_xq  <<<dim3((NN + 127) / 128), 256, 0, stream>>>(x, W_emb, xq);
  k_edge<<<dim3(512, 4), 256, 0, stream>>>(ef_n, ef_e, ef_s, ef_w,
                                           xq, W_edge, agg, out);
  k_node<<<dim3(7, 248), 256, 0, stream>>>(x, agg, W_node, out);
}